// Round 9
// baseline (117.949 us; speedup 1.0000x reference)
//
#include <hip/hip_runtime.h>
#include <hip/hip_fp16.h>

#define NIN 100000
#define NOUT 50000
#define KNB 32            // neighbors per output point
#define CIN 16
#define COUT 32
#define GP 8              // points per tile (2 per wave, 4 waves)
#define ROW2B 2064        // bytes per point row in s_bl: 64*16*2 (f16) + 16 pad
#define WFOFF 65536       // feats16 offset in d_ws
#define NTILES (NOUT / GP)   // 6250
#define PBLK 2048            // persistent blocks

typedef __attribute__((ext_vector_type(8))) _Float16 half8;
typedef __attribute__((ext_vector_type(2))) _Float16 h2v;
typedef __attribute__((ext_vector_type(4))) float f32x4;

__device__ __forceinline__ h2v pmax(h2v a, h2v b) {
  h2v d;
  asm("v_pk_max_f16 %0, %1, %2" : "=v"(d) : "v"(a), "v"(b));
  return d;
}
__device__ __forceinline__ unsigned int pkh(float lo, float hi) {
  union { __half2 h; unsigned int u; } cv;
  cv.h = __floats2half2_rn(lo, hi);
  return cv.u;
}
__device__ __forceinline__ unsigned short f2hbits(float f) {
  union { __half h; unsigned short s; } c; c.h = __float2half_rn(f); return c.s;
}

// blocks 0..127: Wf[s][g][n][j] = f16(W[kc = s*32+g*8+j][n]) (GEMM2 B-frag order)
// blocks 128..: feats f32 -> f16
__global__ void prep_kernel(const float* __restrict__ kern,
                            const float* __restrict__ feats,
                            unsigned short* __restrict__ wf,
                            unsigned short* __restrict__ f16) {
  const int b = blockIdx.x;
  if (b < 128) {
    int idx = b * 256 + threadIdx.x;          // < 32768
    int j = idx & 7;
    int n = (idx >> 3) & 31;
    int g = (idx >> 8) & 3;
    int s = idx >> 10;
    int kc = s * 32 + g * 8 + j;
    wf[idx] = f2hbits(kern[kc * COUT + n]);
  } else {
    int idx = (b - 128) * 256 + threadIdx.x;  // < 1.6e6 exactly
    f16[idx] = f2hbits(feats[idx]);
  }
}

__launch_bounds__(256, 7)
__global__ void cconv_kernel(const unsigned short* __restrict__ feats16,
                             const float* __restrict__ inp_points,
                             const float* __restrict__ out_points,
                             const float* __restrict__ out_extents,
                             const float* __restrict__ scale_compat,
                             const int* __restrict__ nidx,
                             const float* __restrict__ ndist,
                             const unsigned short* __restrict__ wf,
                             const float* __restrict__ bias,
                             float* __restrict__ out) {
  // f16 B matrix; element (t,c) of point p at byte p*ROW2B + t*32 + c*2
  __shared__ __align__(16) char s_bl[GP * ROW2B];              // 16512 B
  __shared__ __align__(4) unsigned short s_tx[GP * KNB];       // 512 B each
  __shared__ __align__(4) unsigned short s_ty[GP * KNB];
  __shared__ __align__(4) unsigned short s_tz[GP * KNB];
  __shared__ __align__(4) unsigned short s_im[GP * KNB];
  __shared__ float s_cacc[GP][COUT];                           // 1024 B
  __shared__ float s_den[GP];                                  // 32 B

  const int tid = threadIdx.x;
  const int wv = tid >> 6;
  const int lane = tid & 63;
  const int c = lane & 15;          // phase-2 frag row (chan) / tap-in-tile
  const int g = lane >> 4;          // phase-2 edge group
  const int h1 = lane >> 5;         // phase-1: which of the wave's 2 points
  const int e1 = lane & 31;         // phase-1: edge within point

  ((float*)s_cacc)[tid] = 0.0f;     // blockDim == GP*COUT == 256 exactly

  int tile = blockIdx.x;

  // ---- prologue: full gather for the first tile ----
  int nbA; float dA, scA;
  unsigned short fpA0, fpA1, fpA2, fpA3, fpA4, fpA5, fpA6, fpA7;
  unsigned short fpA8, fpA9, fpA10, fpA11, fpA12, fpA13, fpA14, fpA15;
  float pxA, pyA, pzA, oxA, oyA, ozA, invA;
  {
    const int e0 = tile * (GP * KNB) + tid;
    nbA = nidx[e0];
    dA = ndist[e0];
    scA = scale_compat[e0];
#define GATHER_F(dst, hh, jj)                                         \
    { const int nb_ = __shfl(nbA, (hh) * 32 + g * 8 + (jj));          \
      dst = feats16[nb_ * CIN + c]; }
    GATHER_F(fpA0, 0, 0) GATHER_F(fpA1, 0, 1) GATHER_F(fpA2, 0, 2) GATHER_F(fpA3, 0, 3)
    GATHER_F(fpA4, 0, 4) GATHER_F(fpA5, 0, 5) GATHER_F(fpA6, 0, 6) GATHER_F(fpA7, 0, 7)
    GATHER_F(fpA8, 1, 0) GATHER_F(fpA9, 1, 1) GATHER_F(fpA10, 1, 2) GATHER_F(fpA11, 1, 3)
    GATHER_F(fpA12, 1, 4) GATHER_F(fpA13, 1, 5) GATHER_F(fpA14, 1, 6) GATHER_F(fpA15, 1, 7)
#undef GATHER_F
    const int pg = tile * GP + wv * 2 + h1;
    pxA = inp_points[nbA * 3 + 0];
    pyA = inp_points[nbA * 3 + 1];
    pzA = inp_points[nbA * 3 + 2];
    oxA = out_points[pg * 3 + 0];
    oyA = out_points[pg * 3 + 1];
    ozA = out_points[pg * 3 + 2];
    invA = 1.0f / (0.5f * out_extents[pg]);
  }

  while (true) {
    const int tnext = tile + PBLK;
    const bool hasN = tnext < NTILES;   // block-uniform

    // ---- step A: issue next-tile edge streams (latency hides under 1+2) ----
    int nbB = 0; float dB = 0.f, scB = 0.f;
    if (hasN) {
      const int e0 = tnext * (GP * KNB) + tid;
      nbB = nidx[e0];
      dB = ndist[e0];
      scB = scale_compat[e0];
    }

    // ---- phase 1: geometry for cur, all from registers ----
    {
      float q = 1.0f - dA * dA;
      float w6 = q * q * q;
      w6 = fminf(fmaxf(w6, 0.0f), 1.0f);
      const float imp = scA * w6;
      const float rx = (pxA - oxA) * invA;
      const float ry = (pyA - oyA) * invA;
      const float rz = (pzA - ozA) * invA;
      const float r = sqrtf(rx * rx + ry * ry + rz * rz);
      const float linf = fmaxf(fabsf(rx), fmaxf(fabsf(ry), fabsf(rz)));
      const float sf = r / fmaxf(linf, 1e-12f);
      const float tx = fminf(fmaxf((rx * sf * 0.5f + 0.5f) * 3.0f, 0.0f), 3.0f);
      const float ty = fminf(fmaxf((ry * sf * 0.5f + 0.5f) * 3.0f, 0.0f), 3.0f);
      const float tz = fminf(fmaxf((rz * sf * 0.5f + 0.5f) * 3.0f, 0.0f), 3.0f);

      // write index == tid; 2B stride -> 2 lanes/bank (free)
      s_tx[tid] = f2hbits(tx);
      s_ty[tid] = f2hbits(ty);
      s_tz[tid] = f2hbits(tz);
      s_im[tid] = f2hbits(imp);

      float dsum = imp;               // reduce within each 32-lane half
#pragma unroll
      for (int m = 1; m < 32; m <<= 1) dsum += __shfl_xor(dsum, m);
      if (e1 == 0) s_den[wv * 2 + h1] = dsum;
    }
    // NO barrier: phase 2 reads only this wave's own edge rows.

    // ---- phase 2: per-point GEMM1 (transposed), packed-f16 hat math ----
    {
      const _Float16 kys = (_Float16)(short)(c >> 2);
      const _Float16 kzs = (_Float16)(short)(c & 3);
      const h2v z2 = {(_Float16)0, (_Float16)0};
      const h2v one2 = {(_Float16)1, (_Float16)1};
      const h2v two2 = {(_Float16)2, (_Float16)2};
      const h2v ky2 = {kys, kys};
      const h2v kz2 = {kzs, kzs};
#pragma unroll
      for (int h = 0; h < 2; ++h) {
        const int p = wv * 2 + h;
        union { unsigned int u[4]; h2v h[4]; half8 v; } wfr0, wfr1, wfr2, wfr3, fef;
#pragma unroll
        for (int jp = 0; jp < 4; ++jp) {     // edge pair: e = g*8 + 2jp, +1
          const int eb = p * KNB + g * 8 + jp * 2;
          const h2v tx2 = *(const h2v*)&s_tx[eb];
          const h2v ty2 = *(const h2v*)&s_ty[eb];
          const h2v tz2 = *(const h2v*)&s_tz[eb];
          const h2v im2 = *(const h2v*)&s_im[eb];
          h2v t = ty2 - ky2;
          h2v at = pmax(t, z2 - t);                  // |ty - ky|
          const h2v hy = pmax(z2, one2 - at);
          t = tz2 - kz2;
          at = pmax(t, z2 - t);
          const h2v hz = pmax(z2, one2 - at);
          const h2v m2 = hy * hz * im2;
          const h2v w0 = pmax(z2, one2 - tx2) * m2;  // tx >= 0
          t = tx2 - one2;
          at = pmax(t, z2 - t);
          const h2v w1 = pmax(z2, one2 - at) * m2;
          t = tx2 - two2;
          at = pmax(t, z2 - t);
          const h2v w2 = pmax(z2, one2 - at) * m2;
          const h2v w3 = pmax(z2, t) * m2;           // max(0, tx-2), tx <= 3
          wfr0.h[jp] = w0;
          wfr1.h[jp] = w1;
          wfr2.h[jp] = w2;
          wfr3.h[jp] = w3;
        }
        if (h == 0) {
          fef.u[0] = (unsigned)fpA0 | ((unsigned)fpA1 << 16);
          fef.u[1] = (unsigned)fpA2 | ((unsigned)fpA3 << 16);
          fef.u[2] = (unsigned)fpA4 | ((unsigned)fpA5 << 16);
          fef.u[3] = (unsigned)fpA6 | ((unsigned)fpA7 << 16);
        } else {
          fef.u[0] = (unsigned)fpA8 | ((unsigned)fpA9 << 16);
          fef.u[1] = (unsigned)fpA10 | ((unsigned)fpA11 << 16);
          fef.u[2] = (unsigned)fpA12 | ((unsigned)fpA13 << 16);
          fef.u[3] = (unsigned)fpA14 | ((unsigned)fpA15 << 16);
        }
        const f32x4 z = {0.f, 0.f, 0.f, 0.f};
        f32x4 d0 = __builtin_amdgcn_mfma_f32_16x16x32_f16(fef.v, wfr0.v, z, 0, 0, 0);
        f32x4 d1 = __builtin_amdgcn_mfma_f32_16x16x32_f16(fef.v, wfr1.v, z, 0, 0, 0);
        f32x4 d2 = __builtin_amdgcn_mfma_f32_16x16x32_f16(fef.v, wfr2.v, z, 0, 0, 0);
        f32x4 d3 = __builtin_amdgcn_mfma_f32_16x16x32_f16(fef.v, wfr3.v, z, 0, 0, 0);
        // lane holds chans {4g..4g+3} of tap (tile*16 + c); byte = t*32 + chan*2
        char* bp = s_bl + (unsigned)(p * ROW2B + c * 32 + g * 8);
        *(uint2*)(bp + 0 * 512) = make_uint2(pkh(d0[0], d0[1]), pkh(d0[2], d0[3]));
        *(uint2*)(bp + 1 * 512) = make_uint2(pkh(d1[0], d1[1]), pkh(d1[2], d1[3]));
        *(uint2*)(bp + 2 * 512) = make_uint2(pkh(d2[0], d2[1]), pkh(d2[2], d2[3]));
        *(uint2*)(bp + 3 * 512) = make_uint2(pkh(d3[0], d3[1]), pkh(d3[2], d3[3]));
      }
    }

    // ---- step B: issue next-tile gathers; consumed next iteration ----
    unsigned short fpB0 = 0, fpB1 = 0, fpB2 = 0, fpB3 = 0, fpB4 = 0, fpB5 = 0,
                   fpB6 = 0, fpB7 = 0, fpB8 = 0, fpB9 = 0, fpB10 = 0, fpB11 = 0,
                   fpB12 = 0, fpB13 = 0, fpB14 = 0, fpB15 = 0;
    float pxB = 0, pyB = 0, pzB = 0, oxB = 0, oyB = 0, ozB = 0, invB = 0;
    if (hasN) {
#define GATHER_F(dst, hh, jj)                                         \
      { const int nb_ = __shfl(nbB, (hh) * 32 + g * 8 + (jj));        \
        dst = feats16[nb_ * CIN + c]; }
      GATHER_F(fpB0, 0, 0) GATHER_F(fpB1, 0, 1) GATHER_F(fpB2, 0, 2) GATHER_F(fpB3, 0, 3)
      GATHER_F(fpB4, 0, 4) GATHER_F(fpB5, 0, 5) GATHER_F(fpB6, 0, 6) GATHER_F(fpB7, 0, 7)
      GATHER_F(fpB8, 1, 0) GATHER_F(fpB9, 1, 1) GATHER_F(fpB10, 1, 2) GATHER_F(fpB11, 1, 3)
      GATHER_F(fpB12, 1, 4) GATHER_F(fpB13, 1, 5) GATHER_F(fpB14, 1, 6) GATHER_F(fpB15, 1, 7)
#undef GATHER_F
      const int pg = tnext * GP + wv * 2 + h1;
      pxB = inp_points[nbB * 3 + 0];
      pyB = inp_points[nbB * 3 + 1];
      pzB = inp_points[nbB * 3 + 2];
      oxB = out_points[pg * 3 + 0];
      oyB = out_points[pg * 3 + 1];
      ozB = out_points[pg * 3 + 2];
      invB = 1.0f / (0.5f * out_extents[pg]);
    }

    __syncthreads();

    // ---- phase 3: GEMM2. M-frame 16 (8 valid), N=32, K=1024 over 4 waves ----
    f32x4 acc0 = {0.f, 0.f, 0.f, 0.f}, acc1 = {0.f, 0.f, 0.f, 0.f};
    const int pl = lane & 15;
    const int arow = pl & (GP - 1);
    const int g4 = lane >> 4;
#pragma unroll
    for (int ss = 0; ss < 8; ++ss) {
      const int s = wv * 8 + ss;
      const half8 a = *(const half8*)(s_bl + arow * ROW2B + s * 64 + g4 * 16);
      const half8 b0 = *(const half8*)(wf + ((unsigned)((s * 4 + g4) * 32) + pl) * 8);
      const half8 b1 = *(const half8*)(wf + ((unsigned)((s * 4 + g4) * 32) + 16 + pl) * 8);
      acc0 = __builtin_amdgcn_mfma_f32_16x16x32_f16(a, b0, acc0, 0, 0, 0);
      acc1 = __builtin_amdgcn_mfma_f32_16x16x32_f16(a, b1, acc1, 0, 0, 0);
    }
#pragma unroll
    for (int j = 0; j < 4; ++j) {
      const int row = g4 * 4 + j;
      if (row < GP) {
        atomicAdd(&s_cacc[row][pl], acc0[j]);
        atomicAdd(&s_cacc[row][pl + 16], acc1[j]);
      }
    }

    __syncthreads();

    // ---- epilogue: normalize, bias, relu; re-zero s_cacc for next iter ----
    {
      const int p = tid >> 5;
      const int dch = tid & 31;
      const float den = s_den[p];
      float v = ((float*)s_cacc)[tid] / (den > 0.0f ? den : 1.0f) + bias[dch];
      out[tile * (GP * COUT) + tid] = fmaxf(v, 0.0f);
      ((float*)s_cacc)[tid] = 0.0f;
    }

    if (!hasN) break;
    __syncthreads();   // s_cacc re-zero + s_* buffers safe for next iteration

    // ---- rotate pipeline registers ----
    tile = tnext;
    nbA = nbB; dA = dB; scA = scB;
    fpA0 = fpB0; fpA1 = fpB1; fpA2 = fpB2; fpA3 = fpB3;
    fpA4 = fpB4; fpA5 = fpB5; fpA6 = fpB6; fpA7 = fpB7;
    fpA8 = fpB8; fpA9 = fpB9; fpA10 = fpB10; fpA11 = fpB11;
    fpA12 = fpB12; fpA13 = fpB13; fpA14 = fpB14; fpA15 = fpB15;
    pxA = pxB; pyA = pyB; pzA = pzB;
    oxA = oxB; oyA = oyB; ozA = ozB; invA = invB;
  }
}

extern "C" void kernel_launch(void* const* d_in, const int* in_sizes, int n_in,
                              void* d_out, int out_size, void* d_ws, size_t ws_size,
                              hipStream_t stream) {
  const float* feats        = (const float*)d_in[0];
  const float* inp_points   = (const float*)d_in[1];
  const float* out_points   = (const float*)d_in[2];
  const float* out_extents  = (const float*)d_in[3];
  const float* scale_compat = (const float*)d_in[4];
  const int*   nidx         = (const int*)d_in[5];
  const float* ndist        = (const float*)d_in[7];
  const float* kern         = (const float*)d_in[8];
  const float* bias         = (const float*)d_in[9];
  unsigned short* wf  = (unsigned short*)d_ws;                    // 64 KiB
  unsigned short* f16 = (unsigned short*)((char*)d_ws + WFOFF);   // 3.2 MB

  prep_kernel<<<128 + (NIN * CIN) / 256, 256, 0, stream>>>(kern, feats, wf, f16);
  cconv_kernel<<<PBLK, 256, 0, stream>>>(f16, inp_points, out_points,
                                         out_extents, scale_compat, nidx,
                                         ndist, wf, bias, (float*)d_out);
}

// Round 10
// 70.274 us; speedup vs baseline: 1.6784x; 1.6784x over previous
//
#include <hip/hip_runtime.h>
#include <hip/hip_fp16.h>

#define NIN 100000
#define NOUT 50000
#define KNB 32            // neighbors per output point
#define CIN 16
#define COUT 32
#define GP 8              // points per block (2 per wave, 4 waves)
#define ROW2B 2064        // bytes per point row in s_bl: 64*16*2 (f16) + 16 pad
#define WFOFF 65536       // feats16 offset in d_ws

typedef __attribute__((ext_vector_type(8))) _Float16 half8;
typedef __attribute__((ext_vector_type(2))) _Float16 h2v;
typedef __attribute__((ext_vector_type(4))) float f32x4;

__device__ __forceinline__ h2v pmax(h2v a, h2v b) {
  h2v d;
  asm("v_pk_max_f16 %0, %1, %2" : "=v"(d) : "v"(a), "v"(b));
  return d;
}
__device__ __forceinline__ unsigned int pkh(float lo, float hi) {
  union { __half2 h; unsigned int u; } cv;
  cv.h = __floats2half2_rn(lo, hi);
  return cv.u;
}
__device__ __forceinline__ unsigned short f2hbits(float f) {
  union { __half h; unsigned short s; } c; c.h = __float2half_rn(f); return c.s;
}

// blocks 0..127: Wf[s][g][n][j] = f16(W[kc = s*32+g*8+j][n]) (GEMM2 B-frag order)
// blocks 128..: feats f32 -> f16 (only when do_feats)
__global__ void prep_kernel(const float* __restrict__ kern,
                            const float* __restrict__ feats,
                            unsigned short* __restrict__ wf,
                            unsigned short* __restrict__ f16,
                            int do_feats) {
  const int b = blockIdx.x;
  if (b < 128) {
    int idx = b * 256 + threadIdx.x;          // < 32768
    int j = idx & 7;
    int n = (idx >> 3) & 31;
    int g = (idx >> 8) & 3;
    int s = idx >> 10;
    int kc = s * 32 + g * 8 + j;
    wf[idx] = f2hbits(kern[kc * COUT + n]);
  } else if (do_feats) {
    int idx = (b - 128) * 256 + threadIdx.x;  // < 1.6e6 exactly
    f16[idx] = f2hbits(feats[idx]);
  }
}

template <int F16F>
__launch_bounds__(256, 8)
__global__ void cconv_kernel(const float* __restrict__ featsf,
                             const unsigned short* __restrict__ feats16,
                             const float* __restrict__ inp_points,
                             const float* __restrict__ out_points,
                             const float* __restrict__ out_extents,
                             const float* __restrict__ scale_compat,
                             const int* __restrict__ nidx,
                             const float* __restrict__ ndist,
                             const unsigned short* __restrict__ wf,
                             const float* __restrict__ bias,
                             float* __restrict__ out) {
  // s_bl row p (ROW2B bytes) serves double duty:
  //   phase 0-2a: bytes 0..1023 hold s_fe[p] = staged feats rows [32 edges][16 ch] f16
  //   phase 2b-3: full 2048 B hold the B matrix, element (t,c) at byte t*32 + c*2.
  // Safe because each wave's fef reads of row p complete (in-order LDS) before
  // its D1 writes to the same row, and rows are wave-private until the barrier.
  __shared__ __align__(16) char s_bl[GP * ROW2B];              // 16512 B
  __shared__ __align__(4) unsigned short s_tx[GP * KNB];       // 512 B each
  __shared__ __align__(4) unsigned short s_ty[GP * KNB];
  __shared__ __align__(4) unsigned short s_tz[GP * KNB];
  __shared__ __align__(4) unsigned short s_im[GP * KNB];
  __shared__ float s_cacc[GP][COUT];                           // 1024 B
  __shared__ float s_den[GP];                                  // 32 B

  const int tid = threadIdx.x;
  const int wv = tid >> 6;
  const int lane = tid & 63;
  const int c = lane & 15;          // phase-2 frag row (chan) / tap-in-tile
  const int g = lane >> 4;          // phase-2 edge group

  ((float*)s_cacc)[tid] = 0.0f;     // blockDim == GP*COUT == 256 exactly

  // ---- phase 0: coalesced edge streams + ROW-gather of feats (1 b128 instr
  // per point = 64 addresses, vs 16 scalar gathers = 1024). Rows staged to
  // LDS linearly (lane*16 -> conflict-free). ----
  const int eg0 = blockIdx.x * (GP * KNB) + tid;   // this lane's own edge
  const int my_nb = nidx[eg0];
  const float my_d = ndist[eg0];
  const float my_sc = scale_compat[eg0];
  {
    const int eh = lane >> 1;       // edge this lane fetches
    const int hf = lane & 1;        // which 16B half of the 32B row
#pragma unroll
    for (int h = 0; h < 2; ++h) {
      const int p = wv * 2 + h;
      const int nb_ = __shfl(my_nb, h * 32 + eh);
      if constexpr (F16F) {
        const uint4 row = *(const uint4*)(feats16 + nb_ * CIN + hf * 8);
        *(uint4*)(s_bl + p * ROW2B + lane * 16) = row;
      } else {
        const float4 r0 = *(const float4*)(featsf + nb_ * CIN + hf * 8);
        const float4 r1 = *(const float4*)(featsf + nb_ * CIN + hf * 8 + 4);
        uint4 rw;
        rw.x = pkh(r0.x, r0.y); rw.y = pkh(r0.z, r0.w);
        rw.z = pkh(r1.x, r1.y); rw.w = pkh(r1.z, r1.w);
        *(uint4*)(s_bl + p * ROW2B + lane * 16) = rw;
      }
    }
  }

  // ---- phase 1: geometry; all 64 lanes active (2 points per wave) ----
  {
    const int h = lane >> 5;          // which of the wave's 2 points
    const int e = lane & 31;          // edge
    const int p = wv * 2 + h;         // point-in-block
    const int pg = blockIdx.x * GP + p;
    const int nb = my_nb;
    float q = 1.0f - my_d * my_d;
    float w6 = q * q * q;
    w6 = fminf(fmaxf(w6, 0.0f), 1.0f);
    const float imp = my_sc * w6;

    const float inv = 1.0f / (0.5f * out_extents[pg]);
    const float rx = (inp_points[nb * 3 + 0] - out_points[pg * 3 + 0]) * inv;
    const float ry = (inp_points[nb * 3 + 1] - out_points[pg * 3 + 1]) * inv;
    const float rz = (inp_points[nb * 3 + 2] - out_points[pg * 3 + 2]) * inv;
    const float r = sqrtf(rx * rx + ry * ry + rz * rz);
    const float linf = fmaxf(fabsf(rx), fmaxf(fabsf(ry), fabsf(rz)));
    const float sf = r / fmaxf(linf, 1e-12f);
    const float tx = fminf(fmaxf((rx * sf * 0.5f + 0.5f) * 3.0f, 0.0f), 3.0f);
    const float ty = fminf(fmaxf((ry * sf * 0.5f + 0.5f) * 3.0f, 0.0f), 3.0f);
    const float tz = fminf(fmaxf((rz * sf * 0.5f + 0.5f) * 3.0f, 0.0f), 3.0f);

    // write index p*KNB+e == tid; 2B stride -> 2 lanes/bank (free)
    s_tx[tid] = f2hbits(tx);
    s_ty[tid] = f2hbits(ty);
    s_tz[tid] = f2hbits(tz);
    s_im[tid] = f2hbits(imp);

    float dsum = imp;                 // reduce within each 32-lane half
#pragma unroll
    for (int m = 1; m < 32; m <<= 1) dsum += __shfl_xor(dsum, m);
    if (e == 0) s_den[p] = dsum;
  }
  // NO barrier: phase 2 reads only this wave's own rows (same-wave LDS order).

  // ---- phase 2: per-point GEMM1 (transposed), packed-f16 2-wide hat math.
  // fef rebuilt from staged rows: ch c of edges g*8..g*8+7 (8 u16 reads). ----
  {
    const _Float16 kys = (_Float16)(short)(c >> 2);
    const _Float16 kzs = (_Float16)(short)(c & 3);
    const h2v z2 = {(_Float16)0, (_Float16)0};
    const h2v one2 = {(_Float16)1, (_Float16)1};
    const h2v two2 = {(_Float16)2, (_Float16)2};
    const h2v ky2 = {kys, kys};
    const h2v kz2 = {kzs, kzs};
#pragma unroll
    for (int h = 0; h < 2; ++h) {
      const int p = wv * 2 + h;
      union { unsigned int u[4]; h2v h[4]; half8 v; } wfr0, wfr1, wfr2, wfr3, fef;
      // fef first: consume s_fe[p] (bytes 0..1023 of row p) BEFORE D1 writes
#pragma unroll
      for (int jp = 0; jp < 4; ++jp) {
        const unsigned a0 = (unsigned)(p * ROW2B + (g * 8 + jp * 2) * 32 + c * 2);
        const unsigned short lo = *(const unsigned short*)(s_bl + a0);
        const unsigned short hi = *(const unsigned short*)(s_bl + a0 + 32);
        fef.u[jp] = (unsigned)lo | ((unsigned)hi << 16);
      }
#pragma unroll
      for (int jp = 0; jp < 4; ++jp) {       // edge pair: e = g*8 + 2jp, +1
        const int eb = p * KNB + g * 8 + jp * 2;
        const h2v tx2 = *(const h2v*)&s_tx[eb];
        const h2v ty2 = *(const h2v*)&s_ty[eb];
        const h2v tz2 = *(const h2v*)&s_tz[eb];
        const h2v im2 = *(const h2v*)&s_im[eb];
        h2v t = ty2 - ky2;
        h2v at = pmax(t, z2 - t);                    // |ty - ky|
        const h2v hy = pmax(z2, one2 - at);
        t = tz2 - kz2;
        at = pmax(t, z2 - t);
        const h2v hz = pmax(z2, one2 - at);
        const h2v m2 = hy * hz * im2;
        const h2v w0 = pmax(z2, one2 - tx2) * m2;    // tx >= 0
        t = tx2 - one2;
        at = pmax(t, z2 - t);
        const h2v w1 = pmax(z2, one2 - at) * m2;
        t = tx2 - two2;
        at = pmax(t, z2 - t);
        const h2v w2 = pmax(z2, one2 - at) * m2;
        const h2v w3 = pmax(z2, t) * m2;             // max(0, tx-2), tx <= 3
        wfr0.h[jp] = w0;
        wfr1.h[jp] = w1;
        wfr2.h[jp] = w2;
        wfr3.h[jp] = w3;
      }
      const f32x4 z = {0.f, 0.f, 0.f, 0.f};
      f32x4 d0 = __builtin_amdgcn_mfma_f32_16x16x32_f16(fef.v, wfr0.v, z, 0, 0, 0);
      f32x4 d1 = __builtin_amdgcn_mfma_f32_16x16x32_f16(fef.v, wfr1.v, z, 0, 0, 0);
      f32x4 d2 = __builtin_amdgcn_mfma_f32_16x16x32_f16(fef.v, wfr2.v, z, 0, 0, 0);
      f32x4 d3 = __builtin_amdgcn_mfma_f32_16x16x32_f16(fef.v, wfr3.v, z, 0, 0, 0);
      // lane holds chans {4g..4g+3} of tap (tile*16 + c); byte = t*32 + chan*2
      char* bp = s_bl + (unsigned)(p * ROW2B + c * 32 + g * 8);
      *(uint2*)(bp + 0 * 512) = make_uint2(pkh(d0[0], d0[1]), pkh(d0[2], d0[3]));
      *(uint2*)(bp + 1 * 512) = make_uint2(pkh(d1[0], d1[1]), pkh(d1[2], d1[3]));
      *(uint2*)(bp + 2 * 512) = make_uint2(pkh(d2[0], d2[1]), pkh(d2[2], d2[3]));
      *(uint2*)(bp + 3 * 512) = make_uint2(pkh(d3[0], d3[1]), pkh(d3[2], d3[3]));
    }
  }

  __syncthreads();

  // ---- phase 3: GEMM2. M-frame 16 (8 valid points), N = 32, K = 1024 over
  // 4 waves (8 ksteps of 32 each); A-frag is a raw b128 f16 read. ----
  f32x4 acc0 = {0.f, 0.f, 0.f, 0.f}, acc1 = {0.f, 0.f, 0.f, 0.f};
  const int pl = lane & 15;          // A row (mod GP) / B col selector
  const int arow = pl & (GP - 1);    // only GP point-rows exist
  const int g4 = lane >> 4;
#pragma unroll
  for (int ss = 0; ss < 8; ++ss) {
    const int s = wv * 8 + ss;
    const half8 a = *(const half8*)(s_bl + arow * ROW2B + s * 64 + g4 * 16);
    const half8 b0 = *(const half8*)(wf + ((unsigned)((s * 4 + g4) * 32) + pl) * 8);
    const half8 b1 = *(const half8*)(wf + ((unsigned)((s * 4 + g4) * 32) + 16 + pl) * 8);
    acc0 = __builtin_amdgcn_mfma_f32_16x16x32_f16(a, b0, acc0, 0, 0, 0);
    acc1 = __builtin_amdgcn_mfma_f32_16x16x32_f16(a, b1, acc1, 0, 0, 0);
  }
#pragma unroll
  for (int j = 0; j < 4; ++j) {
    const int row = g4 * 4 + j;      // D row = point; rows >= GP are duplicates
    if (row < GP) {
      atomicAdd(&s_cacc[row][pl], acc0[j]);
      atomicAdd(&s_cacc[row][pl + 16], acc1[j]);
    }
  }

  __syncthreads();

  // ---- epilogue: normalize, bias, relu; 256 threads == 256 outputs ----
  {
    const int p = tid >> 5;
    const int dch = tid & 31;
    const float den = s_den[p];
    float v = ((float*)s_cacc)[tid] / (den > 0.0f ? den : 1.0f) + bias[dch];
    out[blockIdx.x * (GP * COUT) + tid] = fmaxf(v, 0.0f);
  }
}

extern "C" void kernel_launch(void* const* d_in, const int* in_sizes, int n_in,
                              void* d_out, int out_size, void* d_ws, size_t ws_size,
                              hipStream_t stream) {
  const float* feats        = (const float*)d_in[0];
  const float* inp_points   = (const float*)d_in[1];
  const float* out_points   = (const float*)d_in[2];
  const float* out_extents  = (const float*)d_in[3];
  const float* scale_compat = (const float*)d_in[4];
  const int*   nidx         = (const int*)d_in[5];
  const float* ndist        = (const float*)d_in[7];
  const float* kern         = (const float*)d_in[8];
  const float* bias         = (const float*)d_in[9];
  unsigned short* wf  = (unsigned short*)d_ws;                    // 64 KiB
  unsigned short* f16 = (unsigned short*)((char*)d_ws + WFOFF);   // 3.2 MB

  const bool f16ok = ws_size >= (size_t)WFOFF + (size_t)NIN * CIN * 2;
  const int prep_blocks = 128 + (f16ok ? (NIN * CIN) / 256 : 0);
  prep_kernel<<<prep_blocks, 256, 0, stream>>>(kern, feats, wf, f16,
                                               f16ok ? 1 : 0);
  if (f16ok)
    cconv_kernel<1><<<NOUT / GP, 256, 0, stream>>>(feats, f16, inp_points,
        out_points, out_extents, scale_compat, nidx, ndist, wf, bias,
        (float*)d_out);
  else
    cconv_kernel<0><<<NOUT / GP, 256, 0, stream>>>(feats, f16, inp_points,
        out_points, out_extents, scale_compat, nidx, ndist, wf, bias,
        (float*)d_out);
}